// Round 11
// baseline (580.148 us; speedup 1.0000x reference)
//
#include <hip/hip_runtime.h>

// LightGCN propagation, MI355X. Round 15.
// R8-R14 evidence: spmm/layer pinned ~155us across FETCH 496/299/167MB ->
// byte-insensitive; BW 29%, VALU 23%, occ 64% (nothing saturated) ->
// LATENCY-CHAIN bound. Old loop: per 16-edge batch, 16 wave-uniform
// broadcast col loads -> waitcnt -> 16 dependent gathers = ~2 round trips
// per 16 edges (~8 RT per 64-edge row ~ 3-4us/wave -> ~80us/pass).
// R15: lane-strided col window - ONE coalesced load fetches 64 indices
// (lane l gets col[w+l]), __shfl broadcasts them in-register, up to 64
// independent gathers issue per window. Chain per window: 1 col RT + 1
// gather RT. Build + mixed formats = R14 verbatim (best measured).
//
// Inputs: [0] user_emb0 [100000,64] f32, [1] item_emb0 [50000,64] f32,
// [2] a_ui_vals [E] f32 (unused; ==1/deg_u), [3] a_iu_vals [E] f32 (unused),
// [4] edge_u [E] i32, [5] edge_i [E] i32.
// Output: user_layers [3,100000,64] then item_layers [3,50000,64], f32 flat.

constexpr int N_USERS = 100000;
constexpr int N_ITEMS = 50000;
constexpr int N_ROWS  = N_USERS + N_ITEMS;   // combined CSR rows
constexpr int D = 64;
constexpr int E_EDGES = 3200000;
constexpr float ALPHA = 0.1f;

constexpr long long NUF = (long long)N_USERS * D;  // 6,400,000
constexpr long long NIF = (long long)N_ITEMS * D;  // 3,200,000

// super-buckets: 256 combined rows each
constexpr int SB_SHIFT = 8;
constexpr int SB_ROWS  = 1 << SB_SHIFT;                       // 256
constexpr int NSB      = (N_ROWS + SB_ROWS - 1) >> SB_SHIFT;  // 586
constexpr int CAP      = 20480;  // static slots per bucket; worst count ~16.9K

constexpr int P1_EDGES   = 8192;
constexpr int P1_THREADS = 512;
constexpr int P1_EPT     = P1_EDGES / P1_THREADS;  // 16
constexpr int P2_THREADS = 512;

// ---------------- output layer 0 ----------------
__global__ void init_layer0(const float* __restrict__ uemb,
                            const float* __restrict__ iemb,
                            float* __restrict__ out) {
    long long idx = (long long)blockIdx.x * blockDim.x + threadIdx.x;
    if (idx < NUF) out[idx] = uemb[idx];
    if (idx < NIF) out[3 * NUF + idx] = iemb[idx];
}

// Fallback-only: seed layers 1,2 with ALPHA*emb0.
__global__ void seed_alpha(const float* __restrict__ uemb,
                           const float* __restrict__ iemb,
                           float* __restrict__ out) {
    long long idx = (long long)blockIdx.x * blockDim.x + threadIdx.x;
    if (idx < NUF) {
        float av = ALPHA * uemb[idx];
        out[NUF + idx] = av;
        out[2 * NUF + idx] = av;
    }
    if (idx < NIF) {
        float av = ALPHA * iemb[idx];
        out[3 * NUF + NIF + idx] = av;
        out[3 * NUF + 2 * NIF + idx] = av;
    }
}

// ---------------- bucket cursors at static offsets ----------------
__global__ void init_sbcur(int* __restrict__ sbcur) {
    int t = blockIdx.x * blockDim.x + threadIdx.x;
    if (t < NSB) sbcur[t] = t * CAP;
}

// After phase1: counts = sbcur[t] - t*CAP; exclusive scan -> sbstart.
__global__ void count_scan(const int* __restrict__ sbcur, int* __restrict__ sbstart) {
    __shared__ int sh[1024];
    int t = threadIdx.x;
    int v = (t < NSB) ? (sbcur[t] - t * CAP) : 0;
    sh[t] = v;
    __syncthreads();
    for (int off = 1; off < 1024; off <<= 1) {
        int x = (t >= off) ? sh[t - off] : 0;
        __syncthreads();
        sh[t] += x;
        __syncthreads();
    }
    if (t < NSB) {
        sbstart[t] = sh[t] - v;
        if (t == NSB - 1) sbstart[NSB] = sh[t];
    }
}

// ---------------- phase 1: bucketed bin-sort (direct scatter, R8/R12) --------
// scratch entry: (local_row << 17) | src   (local_row < 256, src < 2^17)
__global__ void phase1_binsort(const int* __restrict__ eu, const int* __restrict__ ei,
                               int* __restrict__ sbcur, unsigned* __restrict__ scratch) {
    __shared__ int hist[NSB];
    __shared__ int gbase[NSB];
    int t = threadIdx.x;
    int nchunks = (E_EDGES + P1_EDGES - 1) / P1_EDGES;
    for (int c = blockIdx.x; c < nchunks; c += gridDim.x) {
        int lo = c * P1_EDGES;
        for (int r = t; r < NSB; r += P1_THREADS) hist[r] = 0;
        __syncthreads();
        unsigned sbr[2 * P1_EPT];
        unsigned val[2 * P1_EPT];
#pragma unroll
        for (int k = 0; k < P1_EPT; k++) {
            int e = lo + k * P1_THREADS + t;
            if (e < E_EDGES) {
                int u = __builtin_nontemporal_load(eu + e);
                int i = __builtin_nontemporal_load(ei + e);
                int r0 = u;             // user combined row
                int r1 = N_USERS + i;   // item combined row
                int sb0 = r0 >> SB_SHIFT;
                int sb1 = r1 >> SB_SHIFT;
                int rk0 = atomicAdd(&hist[sb0], 1);
                int rk1 = atomicAdd(&hist[sb1], 1);
                sbr[2 * k]     = ((unsigned)sb0 << 16) | (unsigned)rk0;
                val[2 * k]     = ((unsigned)(r0 & (SB_ROWS - 1)) << 17) | (unsigned)i;
                sbr[2 * k + 1] = ((unsigned)sb1 << 16) | (unsigned)rk1;
                val[2 * k + 1] = ((unsigned)(r1 & (SB_ROWS - 1)) << 17) | (unsigned)u;
            } else {
                sbr[2 * k]     = 0xFFFFFFFFu;
                sbr[2 * k + 1] = 0xFFFFFFFFu;
            }
        }
        __syncthreads();
        for (int r = t; r < NSB; r += P1_THREADS) {
            int cnt = hist[r];
            gbase[r] = cnt ? atomicAdd(&sbcur[r], cnt) : 0;
        }
        __syncthreads();
#pragma unroll
        for (int k = 0; k < 2 * P1_EPT; k++) {
            if (sbr[k] != 0xFFFFFFFFu) {
                int sb = (int)(sbr[k] >> 16);
                int rk = (int)(sbr[k] & 0xFFFFu);
                int p  = gbase[sb] + rk;
                if (p < (sb + 1) * CAP)  // OOB guard (never triggers: 32-sigma)
                    scratch[p] = val[k];
            }
        }
        __syncthreads();
    }
}

// ---------------- phase 2: per-bucket LDS reorder -> row[] + streaming col[] --
__global__ void phase2_fused(const unsigned* __restrict__ scratch,
                             const int* __restrict__ sbcur,
                             const int* __restrict__ sbstart,
                             int* __restrict__ row, int* __restrict__ col) {
    __shared__ unsigned buf[CAP];
    __shared__ int hist[SB_ROWS];
    __shared__ int pscan[SB_ROWS];
    int sb = blockIdx.x;
    int t = threadIdx.x;
    int lo = sb * CAP;
    int n  = sbcur[sb] - lo;
    if (n > CAP) n = CAP;            // guard (never triggers)
    int out_lo = sbstart[sb];
    if (t < SB_ROWS) hist[t] = 0;
    __syncthreads();
    for (int idx = t; idx < n; idx += P2_THREADS)
        atomicAdd(&hist[scratch[lo + idx] >> 17], 1);
    __syncthreads();
    if (t < SB_ROWS) pscan[t] = hist[t];
    __syncthreads();
    for (int off = 1; off < SB_ROWS; off <<= 1) {
        int x = 0;
        if (t < SB_ROWS && t >= off) x = pscan[t - off];
        __syncthreads();
        if (t < SB_ROWS) pscan[t] += x;
        __syncthreads();
    }
    int excl = 0;
    if (t < SB_ROWS) {
        excl = pscan[t] - hist[t];
        int gr = (sb << SB_SHIFT) + t;
        if (gr <= N_ROWS) row[gr] = out_lo + excl;  // also covers row[N_ROWS]
    }
    __syncthreads();
    if (t < SB_ROWS) hist[t] = excl;  // becomes the write cursor
    __syncthreads();
    for (int idx = t; idx < n; idx += P2_THREADS) {
        unsigned e = scratch[lo + idx];
        int p = atomicAdd(&hist[e >> 17], 1);
        buf[p] = e & 0x1FFFFu;
    }
    __syncthreads();
    for (int k = t; k < n; k += P2_THREADS)
        col[out_lo + k] = (int)buf[k];
}

// ---------------- emb0 -> mixed tables: user int8+scale, item fp16 -----------
__global__ void emb_convert_mixed(const float* __restrict__ uemb,
                                  const float* __restrict__ iemb,
                                  signed char* __restrict__ q0u,
                                  float* __restrict__ s0u,
                                  _Float16* __restrict__ h0i) {
    long long gtid = (long long)blockIdx.x * blockDim.x + threadIdx.x;
    int wave = (int)(gtid >> 6);
    int lane = (int)(gtid & 63);
    if (wave >= N_ROWS) return;
    if (wave < N_USERS) {
        long long li = ((long long)wave << 6) + lane;
        float v = uemb[li];
        float av = fabsf(v);
#pragma unroll
        for (int off = 32; off > 0; off >>= 1)
            av = fmaxf(av, __shfl_xor(av, off));
        float sc = (av > 0.f) ? av / 127.f : 1.f;
        q0u[li] = (signed char)rintf(v / sc);
        if (lane == 0) s0u[wave] = sc;
    } else {
        int r = wave - N_USERS;
        long long li = ((long long)r << 6) + lane;
        h0i[li] = (_Float16)iemb[li];
    }
}

// ---------------- user pass: fp16 gather, lane-strided col windows -----------
__global__ void spmm_user_h(const int* __restrict__ row, const int* __restrict__ col,
                            const _Float16* __restrict__ h_item,
                            const float* __restrict__ uemb,
                            float* __restrict__ out_user,
                            signed char* __restrict__ q_out,
                            float* __restrict__ s_out) {
    long long gtid = (long long)blockIdx.x * blockDim.x + threadIdx.x;
    int wave = (int)(gtid >> 6);
    int lane = (int)(gtid & 63);
    if (wave >= N_USERS) return;
    int start = __builtin_amdgcn_readfirstlane(row[wave]);
    int end   = __builtin_amdgcn_readfirstlane(row[wave + 1]);
    int len = end - start;
    float scale = (len > 0) ? 1.0f / (float)len : 0.0f;

    float acc0 = 0.f, acc1 = 0.f, acc2 = 0.f, acc3 = 0.f;
    for (int w = start; w < end; w += 64) {
        int a = w + lane;
        int cv = col[(a < 2 * E_EDGES) ? a : (2 * E_EDGES - 1)];  // 1 coalesced ld
        int wend = end - w;
        if (wend > 64) wend = 64;
#pragma unroll
        for (int sb = 0; sb < 4; sb++) {
            const int kb = sb * 16;
            if (kb < wend) {                   // wave-uniform
                int cnt = wend - kb;
                if (cnt >= 16) {
                    float g[16];
#pragma unroll
                    for (int kk = 0; kk < 16; kk++) {
                        int c = __shfl(cv, kb + kk);
                        g[kk] = (float)h_item[((long long)c << 6) + lane];
                    }
#pragma unroll
                    for (int kk = 0; kk < 16; kk += 4) {
                        acc0 += g[kk];
                        acc1 += g[kk + 1];
                        acc2 += g[kk + 2];
                        acc3 += g[kk + 3];
                    }
                } else {
#pragma unroll
                    for (int kk = 0; kk < 16; kk++) {
                        if (kk < cnt) {        // wave-uniform
                            int c = __shfl(cv, kb + kk);
                            acc0 += (float)h_item[((long long)c << 6) + lane];
                        }
                    }
                }
            }
        }
    }
    long long li = ((long long)wave << 6) + lane;
    float res = scale * ((acc0 + acc1) + (acc2 + acc3)) + ALPHA * uemb[li];
    __builtin_nontemporal_store(res, out_user + li);
    if (q_out) {
        float av = fabsf(res);
#pragma unroll
        for (int off = 32; off > 0; off >>= 1)
            av = fmaxf(av, __shfl_xor(av, off));
        float sc = (av > 0.f) ? av / 127.f : 1.f;
        q_out[li] = (signed char)rintf(res / sc);
        if (lane == 0) s_out[wave] = sc;
    }
}

// ---------------- item pass: int8 gather, lane-strided col windows -----------
__global__ void spmm_item_q(const int* __restrict__ row, const int* __restrict__ col,
                            const signed char* __restrict__ q_user,
                            const float* __restrict__ s_user,
                            const float* __restrict__ iemb,
                            float* __restrict__ out_item,
                            _Float16* __restrict__ h_out) {
    long long gtid = (long long)blockIdx.x * blockDim.x + threadIdx.x;
    int wave = (int)(gtid >> 6);
    int lane = (int)(gtid & 63);
    if (wave >= N_ITEMS) return;
    int crow = N_USERS + wave;
    int start = __builtin_amdgcn_readfirstlane(row[crow]);
    int end   = __builtin_amdgcn_readfirstlane(row[crow + 1]);
    int len = end - start;
    float scale = (len > 0) ? 1.0f / (float)len : 0.0f;

    float acc0 = 0.f, acc1 = 0.f, acc2 = 0.f, acc3 = 0.f;
    for (int w = start; w < end; w += 64) {
        int a = w + lane;
        int cv = col[(a < 2 * E_EDGES) ? a : (2 * E_EDGES - 1)];  // 1 coalesced ld
        int wend = end - w;
        if (wend > 64) wend = 64;
#pragma unroll
        for (int sb = 0; sb < 4; sb++) {
            const int kb = sb * 16;
            if (kb < wend) {                   // wave-uniform
                int cnt = wend - kb;
                if (cnt >= 16) {
                    float g[16];
#pragma unroll
                    for (int kk = 0; kk < 16; kk++) {
                        int c = __shfl(cv, kb + kk);
                        float sc = s_user[c];                          // L2 bcast
                        int   qv = q_user[((long long)c << 6) + lane]; // 1 line/row
                        g[kk] = sc * (float)qv;
                    }
#pragma unroll
                    for (int kk = 0; kk < 16; kk += 4) {
                        acc0 += g[kk];
                        acc1 += g[kk + 1];
                        acc2 += g[kk + 2];
                        acc3 += g[kk + 3];
                    }
                } else {
#pragma unroll
                    for (int kk = 0; kk < 16; kk++) {
                        if (kk < cnt) {        // wave-uniform
                            int c = __shfl(cv, kb + kk);
                            acc0 += s_user[c]
                                  * (float)q_user[((long long)c << 6) + lane];
                        }
                    }
                }
            }
        }
    }
    long long li = ((long long)wave << 6) + lane;
    float res = scale * ((acc0 + acc1) + (acc2 + acc3)) + ALPHA * iemb[li];
    __builtin_nontemporal_store(res, out_item + li);
    if (h_out) h_out[li] = (_Float16)res;
}

// ---------------- f32 pull fallback (tier B) ----------------
__global__ void spmm_pull(const int* __restrict__ row, const int* __restrict__ col,
                          const float* __restrict__ src_user,
                          const float* __restrict__ src_item,
                          const float* __restrict__ uemb, const float* __restrict__ iemb,
                          float* __restrict__ out_user, float* __restrict__ out_item) {
    long long gtid = (long long)blockIdx.x * blockDim.x + threadIdx.x;
    int wave = (int)(gtid >> 6);
    int lane = (int)(gtid & 63);
    if (wave >= N_ROWS) return;
    const float* src; const float* emb0; float* dst; int r;
    if (wave < N_USERS) {
        r = wave; src = src_item; emb0 = uemb; dst = out_user;
    } else {
        r = wave - N_USERS; src = src_user; emb0 = iemb; dst = out_item;
    }
    int start = __builtin_amdgcn_readfirstlane(row[wave]);
    int end   = __builtin_amdgcn_readfirstlane(row[wave + 1]);
    int len = end - start;
    float scale = (len > 0) ? 1.0f / (float)len : 0.0f;
    float acc0 = 0.f, acc1 = 0.f, acc2 = 0.f, acc3 = 0.f;
    int j = start;
    for (; j + 4 <= end; j += 4) {
        int c0 = col[j + 0], c1 = col[j + 1], c2 = col[j + 2], c3 = col[j + 3];
        acc0 += src[((long long)c0 << 6) + lane];
        acc1 += src[((long long)c1 << 6) + lane];
        acc2 += src[((long long)c2 << 6) + lane];
        acc3 += src[((long long)c3 << 6) + lane];
    }
    for (; j < end; j++) {
        int c = col[j];
        acc0 += src[((long long)c << 6) + lane];
    }
    float res = scale * ((acc0 + acc1) + (acc2 + acc3))
              + ALPHA * emb0[((long long)r << 6) + lane];
    dst[((long long)r << 6) + lane] = res;
}

// ---------------- fallback (atomic push) ----------------
__global__ void spmm_layer_atomic(const float* __restrict__ a_ui,
                                  const float* __restrict__ a_iu,
                                  const int* __restrict__ edge_u,
                                  const int* __restrict__ edge_i,
                                  const float* __restrict__ src_user,
                                  const float* __restrict__ src_item,
                                  float* __restrict__ dst_user,
                                  float* __restrict__ dst_item) {
    long long gtid = (long long)blockIdx.x * blockDim.x + threadIdx.x;
    long long wave = gtid >> 6;
    int lane = (int)(gtid & 63);
    if (wave < (long long)E_EDGES) {
        int e = (int)wave;
        int u = edge_u[e];
        int i = edge_i[e];
        float x = a_ui[e] * src_item[(long long)i * D + lane];
        __hip_atomic_fetch_add(dst_user + (long long)u * D + lane, x,
                               __ATOMIC_RELAXED, __HIP_MEMORY_SCOPE_AGENT);
    } else if (wave < 2LL * E_EDGES) {
        int e = (int)(wave - E_EDGES);
        int u = edge_u[e];
        int i = edge_i[e];
        float x = a_iu[e] * src_user[(long long)u * D + lane];
        __hip_atomic_fetch_add(dst_item + (long long)i * D + lane, x,
                               __ATOMIC_RELAXED, __HIP_MEMORY_SCOPE_AGENT);
    }
}

extern "C" void kernel_launch(void* const* d_in, const int* in_sizes, int n_in,
                              void* d_out, int out_size, void* d_ws, size_t ws_size,
                              hipStream_t stream) {
    const float* uemb   = (const float*)d_in[0];
    const float* iemb   = (const float*)d_in[1];
    const float* a_ui   = (const float*)d_in[2];
    const float* a_iu   = (const float*)d_in[3];
    const int*   edge_u = (const int*)d_in[4];
    const int*   edge_i = (const int*)d_in[5];
    float* out = (float*)d_out;

    float* u1 = out + NUF;
    float* u2 = out + 2 * NUF;
    float* i1 = out + 3 * NUF + NIF;
    float* i2 = out + 3 * NUF + 2 * NIF;

    // Padded bucketed scratch aliases u1+u2 (dead until spmm layers):
    // NSB*CAP = 12,001,280 u32 <= 12.8M floats (51.2MB).
    unsigned* scratch = (unsigned*)u1;

    // Layer-0 mixed tables in dead u2 after phase2 consumed scratch:
    // q0u (6.4MB) + s0u (400KB) + h0i (6.4MB) = 13.2MB <= 25.6MB.
    signed char* q0u = (signed char*)u2;
    float*       s0u = (float*)(q0u + NUF);
    _Float16*    h0i = (_Float16*)(s0u + N_USERS);

    size_t base_ints = (size_t)(N_ROWS + 1) + NSB + (NSB + 1) + 2 * (size_t)E_EDGES;
    size_t need_b = base_ints * 4 + 64;
    size_t need_m = need_b + (size_t)NIF * 2        // h1i
                  + (size_t)NUF                     // q1u
                  + (size_t)N_USERS * 4;            // s1u
    bool tier_b = ws_size >= need_b;
    bool tier_m = ws_size >= need_m;

    if (tier_b) {
        int* w = (int*)d_ws;
        int* row     = w;  w += N_ROWS + 1;
        int* sbcur   = w;  w += NSB;
        int* sbstart = w;  w += NSB + 1;
        int* col     = w;  w += 2 * E_EDGES;
        _Float16*    h1i = (_Float16*)w;           // tier M only
        signed char* q1u = (signed char*)(h1i + NIF);
        float*       s1u = (float*)(q1u + NUF);    // NIF*2+NUF bytes %4 == 0

        {
            const int threads = 256;
            const int blocks = (int)((NUF + threads - 1) / threads);
            init_layer0<<<blocks, threads, 0, stream>>>(uemb, iemb, out);
        }
        init_sbcur<<<3, 256, 0, stream>>>(sbcur);
        const int p1_blocks = (E_EDGES + P1_EDGES - 1) / P1_EDGES;  // 391
        phase1_binsort<<<p1_blocks, P1_THREADS, 0, stream>>>(edge_u, edge_i,
                                                             sbcur, scratch);
        count_scan<<<1, 1024, 0, stream>>>(sbcur, sbstart);
        phase2_fused<<<NSB, P2_THREADS, 0, stream>>>(scratch, sbcur, sbstart,
                                                     row, col);

        const int ublocks = (int)(((long long)N_USERS * 64 + 255) / 256);  // 25000
        const int iblocks = (int)(((long long)N_ITEMS * 64 + 255) / 256);  // 12500
        if (tier_m) {
            {   // scratch consumed; build mixed tables in dead u2.
                const long long tthreads = (long long)N_ROWS * 64;
                const int blocks = (int)((tthreads + 255) / 256);
                emb_convert_mixed<<<blocks, 256, 0, stream>>>(uemb, iemb,
                                                              q0u, s0u, h0i);
            }
            // layer 1: user gathers fp16 item table (emit q1u/s1u);
            //          item gathers int8 user table (emit h1i).
            spmm_user_h<<<ublocks, 256, 0, stream>>>(row, col, h0i, uemb,
                                                     u1, q1u, s1u);
            spmm_item_q<<<iblocks, 256, 0, stream>>>(row, col, q0u, s0u, iemb,
                                                     i1, h1i);
            // layer 2 (writes u2 -> clobbers q0u/s0u/h0i, all dead here).
            spmm_user_h<<<ublocks, 256, 0, stream>>>(row, col, h1i, uemb,
                                                     u2, nullptr, nullptr);
            spmm_item_q<<<iblocks, 256, 0, stream>>>(row, col, q1u, s1u, iemb,
                                                     i2, nullptr);
        } else {
            // tier B: f32 pull both layers.
            const long long tthreads = (long long)N_ROWS * 64;
            const int blocks = (int)((tthreads + 255) / 256);
            spmm_pull<<<blocks, 256, 0, stream>>>(row, col, uemb, iemb,
                                                  uemb, iemb, u1, i1);
            spmm_pull<<<blocks, 256, 0, stream>>>(row, col, u1, i1,
                                                  uemb, iemb, u2, i2);
        }
    } else {
        {
            const int threads = 256;
            const int blocks = (int)((NUF + threads - 1) / threads);
            init_layer0<<<blocks, threads, 0, stream>>>(uemb, iemb, out);
            seed_alpha<<<blocks, threads, 0, stream>>>(uemb, iemb, out);
        }
        const int threads = 256;
        const long long total_threads = 2LL * E_EDGES * 64;
        const int blocks = (int)((total_threads + threads - 1) / threads);
        spmm_layer_atomic<<<blocks, threads, 0, stream>>>(a_ui, a_iu, edge_u, edge_i,
                                                          uemb, iemb, u1, i1);
        spmm_layer_atomic<<<blocks, threads, 0, stream>>>(a_ui, a_iu, edge_u, edge_i,
                                                          u1, i1, u2, i2);
    }
}

// Round 12
// 547.780 us; speedup vs baseline: 1.0591x; 1.0591x over previous
//
#include <hip/hip_runtime.h>

// LightGCN propagation, MI355X. Round 16.
// R8-R15 ledger: spmm pass pinned 76-88us across FETCH 496/299/167/121MB,
// fp16/int8/shfl, VALU 15-55% -> request-rate floor ~30G line-req/s
// (R8: 299MB/86us@128B=27G; R14: 167MB/80us@64B=33G). R15 shfl: VALU 55%,
// 88us - REVERTED. Dispatch structure: combined (R8, 541us total) beat
// split (R12/R14, 557-560) by ~15us: 4 serialized boundaries + lost
// row-type mixing.
// R16 = R14 build + data flow, but spmm recombined into ONE kernel/layer
// over all 150K rows with per-row-type mixed formats:
//   user waves: fp16 gather from item table (emit q1u/s1u on layer1)
//   item waves: int8+rowscale gather from user table (emit h1i on layer1)
// Pre-committed closure: >=557 or ~541 -> plateau is real, declare next.
//
// Inputs: [0] user_emb0 [100000,64] f32, [1] item_emb0 [50000,64] f32,
// [2] a_ui_vals [E] f32 (unused; ==1/deg_u), [3] a_iu_vals [E] f32 (unused),
// [4] edge_u [E] i32, [5] edge_i [E] i32.
// Output: user_layers [3,100000,64] then item_layers [3,50000,64], f32 flat.

constexpr int N_USERS = 100000;
constexpr int N_ITEMS = 50000;
constexpr int N_ROWS  = N_USERS + N_ITEMS;   // combined CSR rows
constexpr int D = 64;
constexpr int E_EDGES = 3200000;
constexpr float ALPHA = 0.1f;

constexpr long long NUF = (long long)N_USERS * D;  // 6,400,000
constexpr long long NIF = (long long)N_ITEMS * D;  // 3,200,000

// super-buckets: 256 combined rows each
constexpr int SB_SHIFT = 8;
constexpr int SB_ROWS  = 1 << SB_SHIFT;                       // 256
constexpr int NSB      = (N_ROWS + SB_ROWS - 1) >> SB_SHIFT;  // 586
constexpr int CAP      = 20480;  // static slots per bucket; worst count ~16.9K

constexpr int P1_EDGES   = 8192;
constexpr int P1_THREADS = 512;
constexpr int P1_EPT     = P1_EDGES / P1_THREADS;  // 16
constexpr int P2_THREADS = 512;

// ---------------- output layer 0 ----------------
__global__ void init_layer0(const float* __restrict__ uemb,
                            const float* __restrict__ iemb,
                            float* __restrict__ out) {
    long long idx = (long long)blockIdx.x * blockDim.x + threadIdx.x;
    if (idx < NUF) out[idx] = uemb[idx];
    if (idx < NIF) out[3 * NUF + idx] = iemb[idx];
}

// Fallback-only: seed layers 1,2 with ALPHA*emb0.
__global__ void seed_alpha(const float* __restrict__ uemb,
                           const float* __restrict__ iemb,
                           float* __restrict__ out) {
    long long idx = (long long)blockIdx.x * blockDim.x + threadIdx.x;
    if (idx < NUF) {
        float av = ALPHA * uemb[idx];
        out[NUF + idx] = av;
        out[2 * NUF + idx] = av;
    }
    if (idx < NIF) {
        float av = ALPHA * iemb[idx];
        out[3 * NUF + NIF + idx] = av;
        out[3 * NUF + 2 * NIF + idx] = av;
    }
}

// ---------------- bucket cursors at static offsets ----------------
__global__ void init_sbcur(int* __restrict__ sbcur) {
    int t = blockIdx.x * blockDim.x + threadIdx.x;
    if (t < NSB) sbcur[t] = t * CAP;
}

// After phase1: counts = sbcur[t] - t*CAP; exclusive scan -> sbstart.
__global__ void count_scan(const int* __restrict__ sbcur, int* __restrict__ sbstart) {
    __shared__ int sh[1024];
    int t = threadIdx.x;
    int v = (t < NSB) ? (sbcur[t] - t * CAP) : 0;
    sh[t] = v;
    __syncthreads();
    for (int off = 1; off < 1024; off <<= 1) {
        int x = (t >= off) ? sh[t - off] : 0;
        __syncthreads();
        sh[t] += x;
        __syncthreads();
    }
    if (t < NSB) {
        sbstart[t] = sh[t] - v;
        if (t == NSB - 1) sbstart[NSB] = sh[t];
    }
}

// ---------------- phase 1: bucketed bin-sort (direct scatter, R8/R12) --------
// scratch entry: (local_row << 17) | src   (local_row < 256, src < 2^17)
__global__ void phase1_binsort(const int* __restrict__ eu, const int* __restrict__ ei,
                               int* __restrict__ sbcur, unsigned* __restrict__ scratch) {
    __shared__ int hist[NSB];
    __shared__ int gbase[NSB];
    int t = threadIdx.x;
    int nchunks = (E_EDGES + P1_EDGES - 1) / P1_EDGES;
    for (int c = blockIdx.x; c < nchunks; c += gridDim.x) {
        int lo = c * P1_EDGES;
        for (int r = t; r < NSB; r += P1_THREADS) hist[r] = 0;
        __syncthreads();
        unsigned sbr[2 * P1_EPT];
        unsigned val[2 * P1_EPT];
#pragma unroll
        for (int k = 0; k < P1_EPT; k++) {
            int e = lo + k * P1_THREADS + t;
            if (e < E_EDGES) {
                int u = __builtin_nontemporal_load(eu + e);
                int i = __builtin_nontemporal_load(ei + e);
                int r0 = u;             // user combined row
                int r1 = N_USERS + i;   // item combined row
                int sb0 = r0 >> SB_SHIFT;
                int sb1 = r1 >> SB_SHIFT;
                int rk0 = atomicAdd(&hist[sb0], 1);
                int rk1 = atomicAdd(&hist[sb1], 1);
                sbr[2 * k]     = ((unsigned)sb0 << 16) | (unsigned)rk0;
                val[2 * k]     = ((unsigned)(r0 & (SB_ROWS - 1)) << 17) | (unsigned)i;
                sbr[2 * k + 1] = ((unsigned)sb1 << 16) | (unsigned)rk1;
                val[2 * k + 1] = ((unsigned)(r1 & (SB_ROWS - 1)) << 17) | (unsigned)u;
            } else {
                sbr[2 * k]     = 0xFFFFFFFFu;
                sbr[2 * k + 1] = 0xFFFFFFFFu;
            }
        }
        __syncthreads();
        for (int r = t; r < NSB; r += P1_THREADS) {
            int cnt = hist[r];
            gbase[r] = cnt ? atomicAdd(&sbcur[r], cnt) : 0;
        }
        __syncthreads();
#pragma unroll
        for (int k = 0; k < 2 * P1_EPT; k++) {
            if (sbr[k] != 0xFFFFFFFFu) {
                int sb = (int)(sbr[k] >> 16);
                int rk = (int)(sbr[k] & 0xFFFFu);
                int p  = gbase[sb] + rk;
                if (p < (sb + 1) * CAP)  // OOB guard (never triggers: 32-sigma)
                    scratch[p] = val[k];
            }
        }
        __syncthreads();
    }
}

// ---------------- phase 2: per-bucket LDS reorder -> row[] + streaming col[] --
__global__ void phase2_fused(const unsigned* __restrict__ scratch,
                             const int* __restrict__ sbcur,
                             const int* __restrict__ sbstart,
                             int* __restrict__ row, int* __restrict__ col) {
    __shared__ unsigned buf[CAP];
    __shared__ int hist[SB_ROWS];
    __shared__ int pscan[SB_ROWS];
    int sb = blockIdx.x;
    int t = threadIdx.x;
    int lo = sb * CAP;
    int n  = sbcur[sb] - lo;
    if (n > CAP) n = CAP;            // guard (never triggers)
    int out_lo = sbstart[sb];
    if (t < SB_ROWS) hist[t] = 0;
    __syncthreads();
    for (int idx = t; idx < n; idx += P2_THREADS)
        atomicAdd(&hist[scratch[lo + idx] >> 17], 1);
    __syncthreads();
    if (t < SB_ROWS) pscan[t] = hist[t];
    __syncthreads();
    for (int off = 1; off < SB_ROWS; off <<= 1) {
        int x = 0;
        if (t < SB_ROWS && t >= off) x = pscan[t - off];
        __syncthreads();
        if (t < SB_ROWS) pscan[t] += x;
        __syncthreads();
    }
    int excl = 0;
    if (t < SB_ROWS) {
        excl = pscan[t] - hist[t];
        int gr = (sb << SB_SHIFT) + t;
        if (gr <= N_ROWS) row[gr] = out_lo + excl;  // also covers row[N_ROWS]
    }
    __syncthreads();
    if (t < SB_ROWS) hist[t] = excl;  // becomes the write cursor
    __syncthreads();
    for (int idx = t; idx < n; idx += P2_THREADS) {
        unsigned e = scratch[lo + idx];
        int p = atomicAdd(&hist[e >> 17], 1);
        buf[p] = e & 0x1FFFFu;
    }
    __syncthreads();
    for (int k = t; k < n; k += P2_THREADS)
        col[out_lo + k] = (int)buf[k];
}

// ---------------- emb0 -> mixed tables: user int8+scale, item fp16 -----------
__global__ void emb_convert_mixed(const float* __restrict__ uemb,
                                  const float* __restrict__ iemb,
                                  signed char* __restrict__ q0u,
                                  float* __restrict__ s0u,
                                  _Float16* __restrict__ h0i) {
    long long gtid = (long long)blockIdx.x * blockDim.x + threadIdx.x;
    int wave = (int)(gtid >> 6);
    int lane = (int)(gtid & 63);
    if (wave >= N_ROWS) return;
    if (wave < N_USERS) {
        long long li = ((long long)wave << 6) + lane;
        float v = uemb[li];
        float av = fabsf(v);
#pragma unroll
        for (int off = 32; off > 0; off >>= 1)
            av = fmaxf(av, __shfl_xor(av, off));
        float sc = (av > 0.f) ? av / 127.f : 1.f;
        q0u[li] = (signed char)rintf(v / sc);
        if (lane == 0) s0u[wave] = sc;
    } else {
        int r = wave - N_USERS;
        long long li = ((long long)r << 6) + lane;
        h0i[li] = (_Float16)iemb[li];
    }
}

// ---------------- combined spmm layer: mixed formats, one dispatch -----------
// wave = combined row. user waves: fp16 gather from item table; item waves:
// int8+rowscale gather from user table. Layer-1 call passes emit buffers
// (q_out_u/s_out_u for users, h_out_i for items); layer-2 passes nullptr.
__global__ void spmm_mixed(const int* __restrict__ row, const int* __restrict__ col,
                           const _Float16* __restrict__ h_item,
                           const signed char* __restrict__ q_user,
                           const float* __restrict__ s_user,
                           const float* __restrict__ uemb,
                           const float* __restrict__ iemb,
                           float* __restrict__ out_user,
                           float* __restrict__ out_item,
                           signed char* __restrict__ q_out_u,
                           float* __restrict__ s_out_u,
                           _Float16* __restrict__ h_out_i) {
    long long gtid = (long long)blockIdx.x * blockDim.x + threadIdx.x;
    int wave = (int)(gtid >> 6);
    int lane = (int)(gtid & 63);
    if (wave >= N_ROWS) return;
    int start = __builtin_amdgcn_readfirstlane(row[wave]);
    int end   = __builtin_amdgcn_readfirstlane(row[wave + 1]);
    int len = end - start;
    float scale = (len > 0) ? 1.0f / (float)len : 0.0f;

    float acc0 = 0.f, acc1 = 0.f, acc2 = 0.f, acc3 = 0.f;
    if (wave < N_USERS) {
        // ---- user row: fp16 gather (2 lines/row), 16-deep in flight ----
        int j = start;
        for (; j + 16 <= end; j += 16) {
            int c[16];
#pragma unroll
            for (int k = 0; k < 16; k++)
                c[k] = __builtin_nontemporal_load(col + j + k);
            float g[16];
#pragma unroll
            for (int k = 0; k < 16; k++)
                g[k] = (float)h_item[((long long)c[k] << 6) + lane];
#pragma unroll
            for (int k = 0; k < 16; k += 4) {
                acc0 += g[k];
                acc1 += g[k + 1];
                acc2 += g[k + 2];
                acc3 += g[k + 3];
            }
        }
        for (; j + 4 <= end; j += 4) {
            int c0 = __builtin_nontemporal_load(col + j + 0);
            int c1 = __builtin_nontemporal_load(col + j + 1);
            int c2 = __builtin_nontemporal_load(col + j + 2);
            int c3 = __builtin_nontemporal_load(col + j + 3);
            acc0 += (float)h_item[((long long)c0 << 6) + lane];
            acc1 += (float)h_item[((long long)c1 << 6) + lane];
            acc2 += (float)h_item[((long long)c2 << 6) + lane];
            acc3 += (float)h_item[((long long)c3 << 6) + lane];
        }
        for (; j < end; j++) {
            int c = __builtin_nontemporal_load(col + j);
            acc0 += (float)h_item[((long long)c << 6) + lane];
        }
        long long li = ((long long)wave << 6) + lane;
        float res = scale * ((acc0 + acc1) + (acc2 + acc3)) + ALPHA * uemb[li];
        __builtin_nontemporal_store(res, out_user + li);
        if (q_out_u) {
            float av = fabsf(res);
#pragma unroll
            for (int off = 32; off > 0; off >>= 1)
                av = fmaxf(av, __shfl_xor(av, off));
            float sc = (av > 0.f) ? av / 127.f : 1.f;
            q_out_u[li] = (signed char)rintf(res / sc);
            if (lane == 0) s_out_u[wave] = sc;
        }
    } else {
        // ---- item row: int8 gather (1 line/row) + L2-resident scale ----
        int r = wave - N_USERS;
        int j = start;
        for (; j + 16 <= end; j += 16) {
            int c[16];
#pragma unroll
            for (int k = 0; k < 16; k++)
                c[k] = __builtin_nontemporal_load(col + j + k);
            float g[16];
#pragma unroll
            for (int k = 0; k < 16; k++) {
                float sc = s_user[c[k]];
                int   qv = q_user[((long long)c[k] << 6) + lane];
                g[k] = sc * (float)qv;
            }
#pragma unroll
            for (int k = 0; k < 16; k += 4) {
                acc0 += g[k];
                acc1 += g[k + 1];
                acc2 += g[k + 2];
                acc3 += g[k + 3];
            }
        }
        for (; j + 4 <= end; j += 4) {
            int c0 = __builtin_nontemporal_load(col + j + 0);
            int c1 = __builtin_nontemporal_load(col + j + 1);
            int c2 = __builtin_nontemporal_load(col + j + 2);
            int c3 = __builtin_nontemporal_load(col + j + 3);
            acc0 += s_user[c0] * (float)q_user[((long long)c0 << 6) + lane];
            acc1 += s_user[c1] * (float)q_user[((long long)c1 << 6) + lane];
            acc2 += s_user[c2] * (float)q_user[((long long)c2 << 6) + lane];
            acc3 += s_user[c3] * (float)q_user[((long long)c3 << 6) + lane];
        }
        for (; j < end; j++) {
            int c = __builtin_nontemporal_load(col + j);
            acc0 += s_user[c] * (float)q_user[((long long)c << 6) + lane];
        }
        long long li = ((long long)r << 6) + lane;
        float res = scale * ((acc0 + acc1) + (acc2 + acc3)) + ALPHA * iemb[li];
        __builtin_nontemporal_store(res, out_item + li);
        if (h_out_i) h_out_i[li] = (_Float16)res;
    }
}

// ---------------- f32 pull fallback (tier B) ----------------
__global__ void spmm_pull(const int* __restrict__ row, const int* __restrict__ col,
                          const float* __restrict__ src_user,
                          const float* __restrict__ src_item,
                          const float* __restrict__ uemb, const float* __restrict__ iemb,
                          float* __restrict__ out_user, float* __restrict__ out_item) {
    long long gtid = (long long)blockIdx.x * blockDim.x + threadIdx.x;
    int wave = (int)(gtid >> 6);
    int lane = (int)(gtid & 63);
    if (wave >= N_ROWS) return;
    const float* src; const float* emb0; float* dst; int r;
    if (wave < N_USERS) {
        r = wave; src = src_item; emb0 = uemb; dst = out_user;
    } else {
        r = wave - N_USERS; src = src_user; emb0 = iemb; dst = out_item;
    }
    int start = __builtin_amdgcn_readfirstlane(row[wave]);
    int end   = __builtin_amdgcn_readfirstlane(row[wave + 1]);
    int len = end - start;
    float scale = (len > 0) ? 1.0f / (float)len : 0.0f;
    float acc0 = 0.f, acc1 = 0.f, acc2 = 0.f, acc3 = 0.f;
    int j = start;
    for (; j + 4 <= end; j += 4) {
        int c0 = col[j + 0], c1 = col[j + 1], c2 = col[j + 2], c3 = col[j + 3];
        acc0 += src[((long long)c0 << 6) + lane];
        acc1 += src[((long long)c1 << 6) + lane];
        acc2 += src[((long long)c2 << 6) + lane];
        acc3 += src[((long long)c3 << 6) + lane];
    }
    for (; j < end; j++) {
        int c = col[j];
        acc0 += src[((long long)c << 6) + lane];
    }
    float res = scale * ((acc0 + acc1) + (acc2 + acc3))
              + ALPHA * emb0[((long long)r << 6) + lane];
    dst[((long long)r << 6) + lane] = res;
}

// ---------------- fallback (atomic push) ----------------
__global__ void spmm_layer_atomic(const float* __restrict__ a_ui,
                                  const float* __restrict__ a_iu,
                                  const int* __restrict__ edge_u,
                                  const int* __restrict__ edge_i,
                                  const float* __restrict__ src_user,
                                  const float* __restrict__ src_item,
                                  float* __restrict__ dst_user,
                                  float* __restrict__ dst_item) {
    long long gtid = (long long)blockIdx.x * blockDim.x + threadIdx.x;
    long long wave = gtid >> 6;
    int lane = (int)(gtid & 63);
    if (wave < (long long)E_EDGES) {
        int e = (int)wave;
        int u = edge_u[e];
        int i = edge_i[e];
        float x = a_ui[e] * src_item[(long long)i * D + lane];
        __hip_atomic_fetch_add(dst_user + (long long)u * D + lane, x,
                               __ATOMIC_RELAXED, __HIP_MEMORY_SCOPE_AGENT);
    } else if (wave < 2LL * E_EDGES) {
        int e = (int)(wave - E_EDGES);
        int u = edge_u[e];
        int i = edge_i[e];
        float x = a_iu[e] * src_user[(long long)u * D + lane];
        __hip_atomic_fetch_add(dst_item + (long long)i * D + lane, x,
                               __ATOMIC_RELAXED, __HIP_MEMORY_SCOPE_AGENT);
    }
}

extern "C" void kernel_launch(void* const* d_in, const int* in_sizes, int n_in,
                              void* d_out, int out_size, void* d_ws, size_t ws_size,
                              hipStream_t stream) {
    const float* uemb   = (const float*)d_in[0];
    const float* iemb   = (const float*)d_in[1];
    const float* a_ui   = (const float*)d_in[2];
    const float* a_iu   = (const float*)d_in[3];
    const int*   edge_u = (const int*)d_in[4];
    const int*   edge_i = (const int*)d_in[5];
    float* out = (float*)d_out;

    float* u1 = out + NUF;
    float* u2 = out + 2 * NUF;
    float* i1 = out + 3 * NUF + NIF;
    float* i2 = out + 3 * NUF + 2 * NIF;

    // Padded bucketed scratch aliases u1+u2 (dead until spmm layers):
    // NSB*CAP = 12,001,280 u32 <= 12.8M floats (51.2MB).
    unsigned* scratch = (unsigned*)u1;

    // Layer-0 mixed tables in dead u2 after phase2 consumed scratch:
    // q0u (6.4MB) + s0u (400KB) + h0i (6.4MB) = 13.2MB <= 25.6MB.
    signed char* q0u = (signed char*)u2;
    float*       s0u = (float*)(q0u + NUF);
    _Float16*    h0i = (_Float16*)(s0u + N_USERS);

    size_t base_ints = (size_t)(N_ROWS + 1) + NSB + (NSB + 1) + 2 * (size_t)E_EDGES;
    size_t need_b = base_ints * 4 + 64;
    size_t need_m = need_b + (size_t)NIF * 2        // h1i
                  + (size_t)NUF                     // q1u
                  + (size_t)N_USERS * 4;            // s1u
    bool tier_b = ws_size >= need_b;
    bool tier_m = ws_size >= need_m;

    if (tier_b) {
        int* w = (int*)d_ws;
        int* row     = w;  w += N_ROWS + 1;
        int* sbcur   = w;  w += NSB;
        int* sbstart = w;  w += NSB + 1;
        int* col     = w;  w += 2 * E_EDGES;
        _Float16*    h1i = (_Float16*)w;           // tier M only
        signed char* q1u = (signed char*)(h1i + NIF);
        float*       s1u = (float*)(q1u + NUF);    // NIF*2+NUF bytes %4 == 0

        {
            const int threads = 256;
            const int blocks = (int)((NUF + threads - 1) / threads);
            init_layer0<<<blocks, threads, 0, stream>>>(uemb, iemb, out);
        }
        init_sbcur<<<3, 256, 0, stream>>>(sbcur);
        const int p1_blocks = (E_EDGES + P1_EDGES - 1) / P1_EDGES;  // 391
        phase1_binsort<<<p1_blocks, P1_THREADS, 0, stream>>>(edge_u, edge_i,
                                                             sbcur, scratch);
        count_scan<<<1, 1024, 0, stream>>>(sbcur, sbstart);
        phase2_fused<<<NSB, P2_THREADS, 0, stream>>>(scratch, sbcur, sbstart,
                                                     row, col);

        const long long tthreads = (long long)N_ROWS * 64;
        const int blocks = (int)((tthreads + 255) / 256);
        if (tier_m) {
            // scratch consumed; build mixed tables in dead u2.
            emb_convert_mixed<<<blocks, 256, 0, stream>>>(uemb, iemb,
                                                          q0u, s0u, h0i);
            // layer 1 (combined): users gather h0i, emit q1u/s1u;
            //                     items gather q0u/s0u, emit h1i.
            spmm_mixed<<<blocks, 256, 0, stream>>>(row, col, h0i, q0u, s0u,
                                                   uemb, iemb, u1, i1,
                                                   q1u, s1u, h1i);
            // layer 2 (combined; writes u2 -> clobbers dead q0u/s0u/h0i).
            spmm_mixed<<<blocks, 256, 0, stream>>>(row, col, h1i, q1u, s1u,
                                                   uemb, iemb, u2, i2,
                                                   nullptr, nullptr, nullptr);
        } else {
            // tier B: f32 pull both layers.
            spmm_pull<<<blocks, 256, 0, stream>>>(row, col, uemb, iemb,
                                                  uemb, iemb, u1, i1);
            spmm_pull<<<blocks, 256, 0, stream>>>(row, col, u1, i1,
                                                  uemb, iemb, u2, i2);
        }
    } else {
        {
            const int threads = 256;
            const int blocks = (int)((NUF + threads - 1) / threads);
            init_layer0<<<blocks, threads, 0, stream>>>(uemb, iemb, out);
            seed_alpha<<<blocks, threads, 0, stream>>>(uemb, iemb, out);
        }
        const int threads = 256;
        const long long total_threads = 2LL * E_EDGES * 64;
        const int blocks = (int)((total_threads + threads - 1) / threads);
        spmm_layer_atomic<<<blocks, threads, 0, stream>>>(a_ui, a_iu, edge_u, edge_i,
                                                          uemb, iemb, u1, i1);
        spmm_layer_atomic<<<blocks, threads, 0, stream>>>(a_ui, a_iu, edge_u, edge_i,
                                                          u1, i1, u2, i2);
    }
}